// Round 1
// baseline (7838.214 us; speedup 1.0000x reference)
//
#include <hip/hip_runtime.h>
#include <math.h>

#define H 1024
#define W 1024
#define B 8
#define TOPK 4096
#define CAP 131072
#define TS 32

// ---------------- NMS pass 0: max_mask = scores == maxpool5(scores) ----------------
__global__ __launch_bounds__(1024) void k_init(const float* __restrict__ scores,
                                               unsigned char* __restrict__ mask) {
    __shared__ float s[36][36];
    int b = blockIdx.z;
    int bx = blockIdx.x * TS, by = blockIdx.y * TS;
    const float* img = scores + (size_t)b * H * W;
    int tid = threadIdx.y * TS + threadIdx.x;
    for (int i = tid; i < 36 * 36; i += 1024) {
        int ly = i / 36, lx = i % 36;
        int gy = by + ly - 2, gx = bx + lx - 2;
        float v = -INFINITY;
        if (gy >= 0 && gy < H && gx >= 0 && gx < W) v = img[gy * W + gx];
        s[ly][lx] = v;
    }
    __syncthreads();
    int ty = threadIdx.y, tx = threadIdx.x;
    float c = s[ty + 2][tx + 2];
    float m = -INFINITY;
#pragma unroll
    for (int dy = 0; dy < 5; ++dy)
#pragma unroll
        for (int dx = 0; dx < 5; ++dx) m = fmaxf(m, s[ty + dy][tx + dx]);
    mask[(size_t)b * H * W + (size_t)(by + ty) * W + (bx + tx)] = (c == m) ? 1 : 0;
}

// ---------- NMS iteration: supp = dilate(mask); ss = supp?0:s; new max of ss ----------
__global__ __launch_bounds__(1024) void k_iter(const float* __restrict__ scores,
                                               const unsigned char* __restrict__ mask_in,
                                               unsigned char* __restrict__ mask_out) {
    __shared__ float s[40][40];
    __shared__ unsigned char m[40][40];
    __shared__ unsigned char supp[40][40];
    __shared__ float ss[40][40];
    int b = blockIdx.z;
    int bx = blockIdx.x * TS, by = blockIdx.y * TS;
    const float* img = scores + (size_t)b * H * W;
    const unsigned char* msk = mask_in + (size_t)b * H * W;
    int tid = threadIdx.y * TS + threadIdx.x;
    for (int i = tid; i < 40 * 40; i += 1024) {
        int ly = i / 40, lx = i % 40;
        int gy = by + ly - 4, gx = bx + lx - 4;
        float v = -INFINITY;
        unsigned char mm = 0;
        if (gy >= 0 && gy < H && gx >= 0 && gx < W) {
            v = img[gy * W + gx];
            mm = msk[gy * W + gx];
        }
        s[ly][lx] = v;
        m[ly][lx] = mm;
    }
    __syncthreads();
    // supp + suppressed scores over the [2,38) x [2,38) region
    for (int i = tid; i < 36 * 36; i += 1024) {
        int ly = 2 + i / 36, lx = 2 + i % 36;
        unsigned char o = 0;
#pragma unroll
        for (int dy = -2; dy <= 2; ++dy)
#pragma unroll
            for (int dx = -2; dx <= 2; ++dx) o |= m[ly + dy][lx + dx];
        supp[ly][lx] = o;
        float v = s[ly][lx];
        ss[ly][lx] = (v == -INFINITY) ? -INFINITY : (o ? 0.0f : v);
    }
    __syncthreads();
    int ty = threadIdx.y, tx = threadIdx.x;
    int cy = ty + 4, cx = tx + 4;
    float c = ss[cy][cx];
    float mx = -INFINITY;
#pragma unroll
    for (int dy = -2; dy <= 2; ++dy)
#pragma unroll
        for (int dx = -2; dx <= 2; ++dx) mx = fmaxf(mx, ss[cy + dy][cx + dx]);
    unsigned char nm = (c == mx && !supp[cy][cx]) ? 1 : 0;
    mask_out[(size_t)b * H * W + (size_t)(by + ty) * W + (bx + tx)] =
        (unsigned char)(m[cy][cx] | nm);
}

// ---------------- Compact survivors (mask & score>0 & not border) ----------------
__global__ void k_compact(const float* __restrict__ scores,
                          const unsigned char* __restrict__ mask,
                          unsigned long long* __restrict__ surv,
                          unsigned int* __restrict__ cnt) {
    size_t gid = (size_t)blockIdx.x * blockDim.x + threadIdx.x;
    if (gid >= (size_t)B * H * W) return;
    if (!mask[gid]) return;
    unsigned int p = (unsigned int)(gid & (H * W - 1));
    int b = (int)(gid >> 20);
    int y = (int)(p >> 10), x = (int)(p & 1023);
    if (y < 2 || y >= H - 2 || x < 2 || x >= W - 2) return;
    float v = scores[gid];
    if (!(v > 0.0f)) return;
    unsigned int slot = atomicAdd(&cnt[b], 1u);
    if (slot < CAP) {
        unsigned long long key =
            ((unsigned long long)__float_as_uint(v) << 32) | (unsigned long long)(~p);
        surv[(size_t)b * CAP + slot] = key;
    }
}

// ---------------- Exact 4096-th largest key via MSB radix select ----------------
__global__ void k_select(const unsigned long long* __restrict__ surv,
                         const unsigned int* __restrict__ cnt,
                         unsigned long long* __restrict__ kstar) {
    int b = blockIdx.x;
    const unsigned long long* sv = surv + (size_t)b * CAP;
    unsigned int n = cnt[b];
    if (n > CAP) n = CAP;
    __shared__ unsigned int hist[256];
    __shared__ unsigned long long sh_prefix;
    __shared__ unsigned int sh_rank;
    if (threadIdx.x == 0) {
        sh_prefix = 0ull;
        sh_rank = TOPK;
    }
    __syncthreads();
    if (n <= TOPK) {
        if (threadIdx.x == 0) kstar[b] = 0ull;
        return;
    }
    unsigned long long prefix_mask = 0ull;
    for (int p = 7; p >= 0; --p) {
        for (int i = threadIdx.x; i < 256; i += blockDim.x) hist[i] = 0;
        __syncthreads();
        unsigned long long pref = sh_prefix;
        for (unsigned int i = threadIdx.x; i < n; i += blockDim.x) {
            unsigned long long kk = sv[i];
            if ((kk & prefix_mask) == pref)
                atomicAdd(&hist[(unsigned int)(kk >> (8 * p)) & 255u], 1u);
        }
        __syncthreads();
        if (threadIdx.x == 0) {
            unsigned int rank = sh_rank, cum = 0;
            int v = 0;
            for (v = 255; v >= 0; --v) {
                unsigned int c = hist[v];
                if (cum + c >= rank) {
                    sh_rank = rank - cum;
                    break;
                }
                cum += c;
            }
            if (v < 0) v = 0;
            sh_prefix = pref | ((unsigned long long)(unsigned int)v << (8 * p));
        }
        __syncthreads();
        prefix_mask |= (0xFFull << (8 * p));
    }
    if (threadIdx.x == 0) kstar[b] = sh_prefix;
}

// -------- Final: gather top-4096, bitonic sort desc, compute DKD outputs --------
__global__ __launch_bounds__(1024) void k_final(const float* __restrict__ scores,
                                                const unsigned long long* __restrict__ surv,
                                                const unsigned int* __restrict__ cnt,
                                                const unsigned long long* __restrict__ kstar,
                                                float* __restrict__ out) {
    __shared__ unsigned long long keys[TOPK];
    __shared__ unsigned int sh_cnt;
    int b = blockIdx.x;
    if (threadIdx.x == 0) sh_cnt = 0;
    __syncthreads();
    unsigned int n = cnt[b];
    if (n > CAP) n = CAP;
    unsigned long long ks = kstar[b];
    const unsigned long long* sv = surv + (size_t)b * CAP;
    for (unsigned int i = threadIdx.x; i < n; i += blockDim.x) {
        unsigned long long kk = sv[i];
        if (kk >= ks) {
            unsigned int pos = atomicAdd(&sh_cnt, 1u);
            if (pos < TOPK) keys[pos] = kk;
        }
    }
    __syncthreads();
    unsigned int c0 = sh_cnt;
    if (c0 > TOPK) c0 = TOPK;
    for (unsigned int i = c0 + threadIdx.x; i < TOPK; i += blockDim.x) keys[i] = 0ull;
    __syncthreads();
    // bitonic sort, descending
    for (int k = 2; k <= TOPK; k <<= 1) {
        for (int j = k >> 1; j > 0; j >>= 1) {
            for (int p = (int)threadIdx.x; p < TOPK / 2; p += (int)blockDim.x) {
                int i = ((p & ~(j - 1)) << 1) | (p & (j - 1));
                int l = i | j;
                bool desc = ((i & k) == 0);
                unsigned long long a = keys[i], bb = keys[l];
                if ((a < bb) == desc) {
                    keys[i] = bb;
                    keys[l] = a;
                }
            }
            __syncthreads();
        }
    }
    const float* img = scores + (size_t)b * H * W;
    for (int kp = (int)threadIdx.x; kp < TOPK; kp += (int)blockDim.x) {
        unsigned long long key = keys[kp];
        unsigned int idx = ~(unsigned int)(key & 0xFFFFFFFFull);
        int ky = (int)(idx >> 10), kx = (int)(idx & 1023);
        ky = min(max(ky, 2), H - 3);
        kx = min(max(kx, 2), W - 3);
        float patch[25];
        float mx = -INFINITY;
#pragma unroll
        for (int dy = 0; dy < 5; ++dy)
#pragma unroll
            for (int dx = 0; dx < 5; ++dx) {
                float v = img[(ky + dy - 2) * W + (kx + dx - 2)];
                patch[dy * 5 + dx] = v;
                mx = fmaxf(mx, v);
            }
        float e[25];
        float ssum = 0.f, ex = 0.f, ey = 0.f;
#pragma unroll
        for (int p = 0; p < 25; ++p) {
            float t = expf((patch[p] - mx) / 0.1f);
            e[p] = t;
            ssum += t;
            ex += t * (float)((p % 5) - 2);
            ey += t * (float)((p / 5) - 2);
        }
        float xr = ex / ssum, yr = ey / ssum;
        float disp = 0.f;
#pragma unroll
        for (int p = 0; p < 25; ++p) {
            float ddx = ((float)((p % 5) - 2) - xr) * 0.5f;
            float ddy = ((float)((p / 5) - 2) - yr) * 0.5f;
            disp += e[p] * (ddx * ddx + ddy * ddy);
        }
        disp /= ssum;
        float kpx = ((float)kx + xr) / 1023.0f * 2.0f - 1.0f;
        float kpy = ((float)ky + yr) / 1023.0f * 2.0f - 1.0f;
        // bilinear grid_sample, align_corners=True (reconstruct px/py from kpx/kpy as ref does)
        float px = (kpx + 1.0f) * 0.5f * 1023.0f;
        float py = (kpy + 1.0f) * 0.5f * 1023.0f;
        float fx = floorf(px), fy = floorf(py);
        float wx = px - fx, wy = py - fy;
        int x0 = (int)fminf(fmaxf(fx, 0.f), 1023.f);
        int x1 = (int)fminf(fmaxf(fx + 1.f, 0.f), 1023.f);
        int y0 = (int)fminf(fmaxf(fy, 0.f), 1023.f);
        int y1 = (int)fminf(fmaxf(fy + 1.f, 0.f), 1023.f);
        float v00 = img[y0 * W + x0], v01 = img[y0 * W + x1];
        float v10 = img[y1 * W + x0], v11 = img[y1 * W + x1];
        float sc = v00 * (1.f - wx) * (1.f - wy) + v01 * wx * (1.f - wy) +
                   v10 * (1.f - wx) * wy + v11 * wx * wy;
        size_t kb = (size_t)b * TOPK + kp;
        out[kb * 2 + 0] = kpx;
        out[kb * 2 + 1] = kpy;
        out[(size_t)B * TOPK * 2 + kb] = disp;
        out[(size_t)B * TOPK * 3 + kb] = sc;
    }
}

extern "C" void kernel_launch(void* const* d_in, const int* in_sizes, int n_in,
                              void* d_out, int out_size, void* d_ws, size_t ws_size,
                              hipStream_t stream) {
    const float* scores = (const float*)d_in[0];
    float* out = (float*)d_out;
    char* ws = (char*)d_ws;
    unsigned char* mask0 = (unsigned char*)(ws);
    unsigned char* mask1 = (unsigned char*)(ws + (size_t)(8u << 20));
    unsigned long long* surv = (unsigned long long*)(ws + (size_t)(16u << 20));
    unsigned int* cnt = (unsigned int*)(ws + (size_t)(24u << 20));
    unsigned long long* kstar = (unsigned long long*)(ws + (size_t)(24u << 20) + 256);

    hipMemsetAsync(cnt, 0, B * sizeof(unsigned int), stream);

    dim3 blk(TS, TS);
    dim3 grd(W / TS, H / TS, B);
    k_init<<<grd, blk, 0, stream>>>(scores, mask0);
    k_iter<<<grd, blk, 0, stream>>>(scores, mask0, mask1);
    k_iter<<<grd, blk, 0, stream>>>(scores, mask1, mask0);
    k_compact<<<(B * H * W) / 256, 256, 0, stream>>>(scores, mask0, surv, cnt);
    k_select<<<B, 256, 0, stream>>>(surv, cnt, kstar);
    k_final<<<B, 1024, 0, stream>>>(scores, surv, cnt, kstar, out);
}

// Round 2
// 625.231 us; speedup vs baseline: 12.5365x; 12.5365x over previous
//
#include <hip/hip_runtime.h>
#include <math.h>

#define H 1024
#define W 1024
#define B 8
#define TOPK 4096
#define CAP 131072
#define TS 32

// ---------------- NMS pass 0: max_mask = scores == maxpool5(scores) ----------------
__global__ __launch_bounds__(1024) void k_init(const float* __restrict__ scores,
                                               unsigned char* __restrict__ mask) {
    __shared__ float s[36][36];
    int b = blockIdx.z;
    int bx = blockIdx.x * TS, by = blockIdx.y * TS;
    const float* img = scores + (size_t)b * H * W;
    int tid = threadIdx.y * TS + threadIdx.x;
    for (int i = tid; i < 36 * 36; i += 1024) {
        int ly = i / 36, lx = i % 36;
        int gy = by + ly - 2, gx = bx + lx - 2;
        float v = -INFINITY;
        if (gy >= 0 && gy < H && gx >= 0 && gx < W) v = img[gy * W + gx];
        s[ly][lx] = v;
    }
    __syncthreads();
    int ty = threadIdx.y, tx = threadIdx.x;
    float c = s[ty + 2][tx + 2];
    float m = -INFINITY;
#pragma unroll
    for (int dy = 0; dy < 5; ++dy)
#pragma unroll
        for (int dx = 0; dx < 5; ++dx) m = fmaxf(m, s[ty + dy][tx + dx]);
    mask[(size_t)b * H * W + (size_t)(by + ty) * W + (bx + tx)] = (c == m) ? 1 : 0;
}

// ---------- NMS iteration 1: supp = dilate(mask); ss = supp?0:s; mask |= new max ----------
__global__ __launch_bounds__(1024) void k_iter(const float* __restrict__ scores,
                                               const unsigned char* __restrict__ mask_in,
                                               unsigned char* __restrict__ mask_out) {
    __shared__ float s[40][40];
    __shared__ unsigned char m[40][40];
    __shared__ unsigned char supp[40][40];
    __shared__ float ss[40][40];
    int b = blockIdx.z;
    int bx = blockIdx.x * TS, by = blockIdx.y * TS;
    const float* img = scores + (size_t)b * H * W;
    const unsigned char* msk = mask_in + (size_t)b * H * W;
    int tid = threadIdx.y * TS + threadIdx.x;
    for (int i = tid; i < 40 * 40; i += 1024) {
        int ly = i / 40, lx = i % 40;
        int gy = by + ly - 4, gx = bx + lx - 4;
        float v = -INFINITY;
        unsigned char mm = 0;
        if (gy >= 0 && gy < H && gx >= 0 && gx < W) {
            v = img[gy * W + gx];
            mm = msk[gy * W + gx];
        }
        s[ly][lx] = v;
        m[ly][lx] = mm;
    }
    __syncthreads();
    for (int i = tid; i < 36 * 36; i += 1024) {
        int ly = 2 + i / 36, lx = 2 + i % 36;
        unsigned char o = 0;
#pragma unroll
        for (int dy = -2; dy <= 2; ++dy)
#pragma unroll
            for (int dx = -2; dx <= 2; ++dx) o |= m[ly + dy][lx + dx];
        supp[ly][lx] = o;
        float v = s[ly][lx];
        ss[ly][lx] = (v == -INFINITY) ? -INFINITY : (o ? 0.0f : v);
    }
    __syncthreads();
    int ty = threadIdx.y, tx = threadIdx.x;
    int cy = ty + 4, cx = tx + 4;
    float c = ss[cy][cx];
    float mx = -INFINITY;
#pragma unroll
    for (int dy = -2; dy <= 2; ++dy)
#pragma unroll
        for (int dx = -2; dx <= 2; ++dx) mx = fmaxf(mx, ss[cy + dy][cx + dx]);
    unsigned char nm = (c == mx && !supp[cy][cx]) ? 1 : 0;
    mask_out[(size_t)b * H * W + (size_t)(by + ty) * W + (bx + tx)] =
        (unsigned char)(m[cy][cx] | nm);
}

// ---- NMS iteration 2 fused with survivor compaction (block-aggregated atomics) ----
__global__ __launch_bounds__(1024) void k_iter2(const float* __restrict__ scores,
                                                const unsigned char* __restrict__ mask_in,
                                                unsigned long long* __restrict__ surv,
                                                unsigned int* __restrict__ cnt) {
    __shared__ float s[40][40];
    __shared__ unsigned char m[40][40];
    __shared__ unsigned char supp[40][40];
    __shared__ float ss[40][40];
    __shared__ unsigned long long lkeys[1024];
    __shared__ unsigned int lcnt, lbase;
    int b = blockIdx.z;
    int bx = blockIdx.x * TS, by = blockIdx.y * TS;
    const float* img = scores + (size_t)b * H * W;
    const unsigned char* msk = mask_in + (size_t)b * H * W;
    int tid = threadIdx.y * TS + threadIdx.x;
    if (tid == 0) lcnt = 0;
    for (int i = tid; i < 40 * 40; i += 1024) {
        int ly = i / 40, lx = i % 40;
        int gy = by + ly - 4, gx = bx + lx - 4;
        float v = -INFINITY;
        unsigned char mm = 0;
        if (gy >= 0 && gy < H && gx >= 0 && gx < W) {
            v = img[gy * W + gx];
            mm = msk[gy * W + gx];
        }
        s[ly][lx] = v;
        m[ly][lx] = mm;
    }
    __syncthreads();
    for (int i = tid; i < 36 * 36; i += 1024) {
        int ly = 2 + i / 36, lx = 2 + i % 36;
        unsigned char o = 0;
#pragma unroll
        for (int dy = -2; dy <= 2; ++dy)
#pragma unroll
            for (int dx = -2; dx <= 2; ++dx) o |= m[ly + dy][lx + dx];
        supp[ly][lx] = o;
        float v = s[ly][lx];
        ss[ly][lx] = (v == -INFINITY) ? -INFINITY : (o ? 0.0f : v);
    }
    __syncthreads();
    int ty = threadIdx.y, tx = threadIdx.x;
    int cy = ty + 4, cx = tx + 4;
    float c = ss[cy][cx];
    float mx = -INFINITY;
#pragma unroll
    for (int dy = -2; dy <= 2; ++dy)
#pragma unroll
        for (int dx = -2; dx <= 2; ++dx) mx = fmaxf(mx, ss[cy + dy][cx + dx]);
    unsigned char nm = (c == mx && !supp[cy][cx]) ? 1 : 0;
    unsigned char fin = (unsigned char)(m[cy][cx] | nm);
    float v = s[cy][cx];
    int gy = by + ty, gx = bx + tx;
    bool keep = fin && (v > 0.0f) && gy >= 2 && gy < H - 2 && gx >= 2 && gx < W - 2;
    if (keep) {
        unsigned int p = (unsigned int)(gy * W + gx);
        unsigned long long key =
            ((unsigned long long)__float_as_uint(v) << 32) | (unsigned long long)(~p);
        unsigned int pos = atomicAdd(&lcnt, 1u);
        lkeys[pos] = key;
    }
    __syncthreads();
    if (tid == 0) lbase = lcnt ? atomicAdd(&cnt[b], lcnt) : 0u;
    __syncthreads();
    if (tid < (int)lcnt) {
        unsigned int slot = lbase + tid;
        if (slot < CAP) surv[(size_t)b * CAP + slot] = lkeys[tid];
    }
}

// ---------------- Exact 4096-th largest key via MSB radix select ----------------
__global__ __launch_bounds__(1024) void k_select(const unsigned long long* __restrict__ surv,
                                                 const unsigned int* __restrict__ cnt,
                                                 unsigned long long* __restrict__ kstar) {
    int b = blockIdx.x;
    const unsigned long long* sv = surv + (size_t)b * CAP;
    unsigned int n = cnt[b];
    if (n > CAP) n = CAP;
    __shared__ unsigned int hist[256];
    __shared__ unsigned long long sh_prefix;
    __shared__ unsigned int sh_rank;
    if (threadIdx.x == 0) {
        sh_prefix = 0ull;
        sh_rank = TOPK;
    }
    __syncthreads();
    if (n <= TOPK) {
        if (threadIdx.x == 0) kstar[b] = 0ull;
        return;
    }
    unsigned long long prefix_mask = 0ull;
    for (int p = 7; p >= 0; --p) {
        for (int i = threadIdx.x; i < 256; i += blockDim.x) hist[i] = 0;
        __syncthreads();
        unsigned long long pref = sh_prefix;
        for (unsigned int i = threadIdx.x; i < n; i += blockDim.x) {
            unsigned long long kk = sv[i];
            if ((kk & prefix_mask) == pref)
                atomicAdd(&hist[(unsigned int)(kk >> (8 * p)) & 255u], 1u);
        }
        __syncthreads();
        if (threadIdx.x == 0) {
            unsigned int rank = sh_rank, cum = 0;
            int v = 0;
            for (v = 255; v >= 0; --v) {
                unsigned int c = hist[v];
                if (cum + c >= rank) {
                    sh_rank = rank - cum;
                    break;
                }
                cum += c;
            }
            if (v < 0) v = 0;
            sh_prefix = pref | ((unsigned long long)(unsigned int)v << (8 * p));
        }
        __syncthreads();
        prefix_mask |= (0xFFull << (8 * p));
    }
    if (threadIdx.x == 0) kstar[b] = sh_prefix;
}

// -------- Gather top-4096 and bitonic sort desc; write sorted keys to ws --------
__global__ __launch_bounds__(1024) void k_sort(const unsigned long long* __restrict__ surv,
                                               const unsigned int* __restrict__ cnt,
                                               const unsigned long long* __restrict__ kstar,
                                               unsigned long long* __restrict__ sorted) {
    __shared__ unsigned long long keys[TOPK];
    __shared__ unsigned int sh_cnt;
    int b = blockIdx.x;
    if (threadIdx.x == 0) sh_cnt = 0;
    __syncthreads();
    unsigned int n = cnt[b];
    if (n > CAP) n = CAP;
    unsigned long long ks = kstar[b];
    const unsigned long long* sv = surv + (size_t)b * CAP;
    for (unsigned int i = threadIdx.x; i < n; i += blockDim.x) {
        unsigned long long kk = sv[i];
        if (kk >= ks) {
            unsigned int pos = atomicAdd(&sh_cnt, 1u);
            if (pos < TOPK) keys[pos] = kk;
        }
    }
    __syncthreads();
    unsigned int c0 = sh_cnt;
    if (c0 > TOPK) c0 = TOPK;
    for (unsigned int i = c0 + threadIdx.x; i < TOPK; i += blockDim.x) keys[i] = 0ull;
    __syncthreads();
    for (int k = 2; k <= TOPK; k <<= 1) {
        for (int j = k >> 1; j > 0; j >>= 1) {
            for (int p = (int)threadIdx.x; p < TOPK / 2; p += (int)blockDim.x) {
                int i = ((p & ~(j - 1)) << 1) | (p & (j - 1));
                int l = i | j;
                bool desc = ((i & k) == 0);
                unsigned long long a = keys[i], bb = keys[l];
                if ((a < bb) == desc) {
                    keys[i] = bb;
                    keys[l] = a;
                }
            }
            __syncthreads();
        }
    }
    for (int i = (int)threadIdx.x; i < TOPK; i += (int)blockDim.x)
        sorted[(size_t)b * TOPK + i] = keys[i];
}

// -------- Per-keypoint soft-argmax / dispersity / bilinear sample --------
__global__ __launch_bounds__(256) void k_out(const float* __restrict__ scores,
                                             const unsigned long long* __restrict__ sorted,
                                             float* __restrict__ out) {
    int gid = blockIdx.x * 256 + threadIdx.x;
    int b = gid / TOPK;
    int kp = gid & (TOPK - 1);
    const float* img = scores + (size_t)b * H * W;
    unsigned long long key = sorted[(size_t)b * TOPK + kp];
    unsigned int idx = ~(unsigned int)(key & 0xFFFFFFFFull);
    int ky = (int)(idx >> 10), kx = (int)(idx & 1023);
    ky = min(max(ky, 2), H - 3);
    kx = min(max(kx, 2), W - 3);
    float patch[25];
    float mx = -INFINITY;
#pragma unroll
    for (int dy = 0; dy < 5; ++dy)
#pragma unroll
        for (int dx = 0; dx < 5; ++dx) {
            float v = img[(ky + dy - 2) * W + (kx + dx - 2)];
            patch[dy * 5 + dx] = v;
            mx = fmaxf(mx, v);
        }
    float e[25];
    float ssum = 0.f, ex = 0.f, ey = 0.f;
#pragma unroll
    for (int p = 0; p < 25; ++p) {
        float t = expf((patch[p] - mx) / 0.1f);
        e[p] = t;
        ssum += t;
        ex += t * (float)((p % 5) - 2);
        ey += t * (float)((p / 5) - 2);
    }
    float xr = ex / ssum, yr = ey / ssum;
    float disp = 0.f;
#pragma unroll
    for (int p = 0; p < 25; ++p) {
        float ddx = ((float)((p % 5) - 2) - xr) * 0.5f;
        float ddy = ((float)((p / 5) - 2) - yr) * 0.5f;
        disp += e[p] * (ddx * ddx + ddy * ddy);
    }
    disp /= ssum;
    float kpx = ((float)kx + xr) / 1023.0f * 2.0f - 1.0f;
    float kpy = ((float)ky + yr) / 1023.0f * 2.0f - 1.0f;
    float px = (kpx + 1.0f) * 0.5f * 1023.0f;
    float py = (kpy + 1.0f) * 0.5f * 1023.0f;
    float fx = floorf(px), fy = floorf(py);
    float wx = px - fx, wy = py - fy;
    int x0 = (int)fminf(fmaxf(fx, 0.f), 1023.f);
    int x1 = (int)fminf(fmaxf(fx + 1.f, 0.f), 1023.f);
    int y0 = (int)fminf(fmaxf(fy, 0.f), 1023.f);
    int y1 = (int)fminf(fmaxf(fy + 1.f, 0.f), 1023.f);
    float v00 = img[y0 * W + x0], v01 = img[y0 * W + x1];
    float v10 = img[y1 * W + x0], v11 = img[y1 * W + x1];
    float sc = v00 * (1.f - wx) * (1.f - wy) + v01 * wx * (1.f - wy) +
               v10 * (1.f - wx) * wy + v11 * wx * wy;
    size_t kb = (size_t)b * TOPK + kp;
    out[kb * 2 + 0] = kpx;
    out[kb * 2 + 1] = kpy;
    out[(size_t)B * TOPK * 2 + kb] = disp;
    out[(size_t)B * TOPK * 3 + kb] = sc;
}

extern "C" void kernel_launch(void* const* d_in, const int* in_sizes, int n_in,
                              void* d_out, int out_size, void* d_ws, size_t ws_size,
                              hipStream_t stream) {
    const float* scores = (const float*)d_in[0];
    float* out = (float*)d_out;
    char* ws = (char*)d_ws;
    unsigned char* mask0 = (unsigned char*)(ws);
    unsigned char* mask1 = (unsigned char*)(ws + (size_t)(8u << 20));
    unsigned long long* surv = (unsigned long long*)(ws + (size_t)(16u << 20));
    unsigned int* cnt = (unsigned int*)(ws + (size_t)(24u << 20));
    unsigned long long* kstar = (unsigned long long*)(ws + (size_t)(24u << 20) + 256);
    unsigned long long* sorted = (unsigned long long*)(ws + (size_t)(25u << 20));

    hipMemsetAsync(cnt, 0, B * sizeof(unsigned int), stream);

    dim3 blk(TS, TS);
    dim3 grd(W / TS, H / TS, B);
    k_init<<<grd, blk, 0, stream>>>(scores, mask0);
    k_iter<<<grd, blk, 0, stream>>>(scores, mask0, mask1);
    k_iter2<<<grd, blk, 0, stream>>>(scores, mask1, surv, cnt);
    k_select<<<B, 1024, 0, stream>>>(surv, cnt, kstar);
    k_sort<<<B, 1024, 0, stream>>>(surv, cnt, kstar, sorted);
    k_out<<<(B * TOPK) / 256, 256, 0, stream>>>(scores, sorted, out);
}

// Round 3
// 469.394 us; speedup vs baseline: 16.6986x; 1.3320x over previous
//
#include <hip/hip_runtime.h>
#include <math.h>

#define H 1024
#define W 1024
#define B 8
#define TOPK 4096
#define CAP 131072
#define TS 32
#define NB 16384

// ---------------- NMS pass 0: max_mask = scores == maxpool5(scores) ----------------
__global__ __launch_bounds__(1024) void k_init(const float* __restrict__ scores,
                                               unsigned char* __restrict__ mask) {
    __shared__ float s[36][36];
    int b = blockIdx.z;
    int bx = blockIdx.x * TS, by = blockIdx.y * TS;
    const float* img = scores + (size_t)b * H * W;
    int tid = threadIdx.y * TS + threadIdx.x;
    for (int i = tid; i < 36 * 36; i += 1024) {
        int ly = i / 36, lx = i % 36;
        int gy = by + ly - 2, gx = bx + lx - 2;
        float v = -INFINITY;
        if (gy >= 0 && gy < H && gx >= 0 && gx < W) v = img[gy * W + gx];
        s[ly][lx] = v;
    }
    __syncthreads();
    int ty = threadIdx.y, tx = threadIdx.x;
    float c = s[ty + 2][tx + 2];
    float m = -INFINITY;
#pragma unroll
    for (int dy = 0; dy < 5; ++dy)
#pragma unroll
        for (int dx = 0; dx < 5; ++dx) m = fmaxf(m, s[ty + dy][tx + dx]);
    mask[(size_t)b * H * W + (size_t)(by + ty) * W + (bx + tx)] = (c == m) ? 1 : 0;
}

// ---------- NMS iteration 1 ----------
__global__ __launch_bounds__(1024) void k_iter(const float* __restrict__ scores,
                                               const unsigned char* __restrict__ mask_in,
                                               unsigned char* __restrict__ mask_out) {
    __shared__ float s[40][40];
    __shared__ unsigned char m[40][40];
    __shared__ unsigned char supp[40][40];
    __shared__ float ss[40][40];
    int b = blockIdx.z;
    int bx = blockIdx.x * TS, by = blockIdx.y * TS;
    const float* img = scores + (size_t)b * H * W;
    const unsigned char* msk = mask_in + (size_t)b * H * W;
    int tid = threadIdx.y * TS + threadIdx.x;
    for (int i = tid; i < 40 * 40; i += 1024) {
        int ly = i / 40, lx = i % 40;
        int gy = by + ly - 4, gx = bx + lx - 4;
        float v = -INFINITY;
        unsigned char mm = 0;
        if (gy >= 0 && gy < H && gx >= 0 && gx < W) {
            v = img[gy * W + gx];
            mm = msk[gy * W + gx];
        }
        s[ly][lx] = v;
        m[ly][lx] = mm;
    }
    __syncthreads();
    for (int i = tid; i < 36 * 36; i += 1024) {
        int ly = 2 + i / 36, lx = 2 + i % 36;
        unsigned char o = 0;
#pragma unroll
        for (int dy = -2; dy <= 2; ++dy)
#pragma unroll
            for (int dx = -2; dx <= 2; ++dx) o |= m[ly + dy][lx + dx];
        supp[ly][lx] = o;
        float v = s[ly][lx];
        ss[ly][lx] = (v == -INFINITY) ? -INFINITY : (o ? 0.0f : v);
    }
    __syncthreads();
    int ty = threadIdx.y, tx = threadIdx.x;
    int cy = ty + 4, cx = tx + 4;
    float c = ss[cy][cx];
    float mx = -INFINITY;
#pragma unroll
    for (int dy = -2; dy <= 2; ++dy)
#pragma unroll
        for (int dx = -2; dx <= 2; ++dx) mx = fmaxf(mx, ss[cy + dy][cx + dx]);
    unsigned char nm = (c == mx && !supp[cy][cx]) ? 1 : 0;
    mask_out[(size_t)b * H * W + (size_t)(by + ty) * W + (bx + tx)] =
        (unsigned char)(m[cy][cx] | nm);
}

// ---- NMS iteration 2 fused with survivor compaction (block-aggregated atomics) ----
__global__ __launch_bounds__(1024) void k_iter2(const float* __restrict__ scores,
                                                const unsigned char* __restrict__ mask_in,
                                                unsigned long long* __restrict__ surv,
                                                unsigned int* __restrict__ cnt) {
    __shared__ float s[40][40];
    __shared__ unsigned char m[40][40];
    __shared__ unsigned char supp[40][40];
    __shared__ float ss[40][40];
    __shared__ unsigned long long lkeys[1024];
    __shared__ unsigned int lcnt, lbase;
    int b = blockIdx.z;
    int bx = blockIdx.x * TS, by = blockIdx.y * TS;
    const float* img = scores + (size_t)b * H * W;
    const unsigned char* msk = mask_in + (size_t)b * H * W;
    int tid = threadIdx.y * TS + threadIdx.x;
    if (tid == 0) lcnt = 0;
    for (int i = tid; i < 40 * 40; i += 1024) {
        int ly = i / 40, lx = i % 40;
        int gy = by + ly - 4, gx = bx + lx - 4;
        float v = -INFINITY;
        unsigned char mm = 0;
        if (gy >= 0 && gy < H && gx >= 0 && gx < W) {
            v = img[gy * W + gx];
            mm = msk[gy * W + gx];
        }
        s[ly][lx] = v;
        m[ly][lx] = mm;
    }
    __syncthreads();
    for (int i = tid; i < 36 * 36; i += 1024) {
        int ly = 2 + i / 36, lx = 2 + i % 36;
        unsigned char o = 0;
#pragma unroll
        for (int dy = -2; dy <= 2; ++dy)
#pragma unroll
            for (int dx = -2; dx <= 2; ++dx) o |= m[ly + dy][lx + dx];
        supp[ly][lx] = o;
        float v = s[ly][lx];
        ss[ly][lx] = (v == -INFINITY) ? -INFINITY : (o ? 0.0f : v);
    }
    __syncthreads();
    int ty = threadIdx.y, tx = threadIdx.x;
    int cy = ty + 4, cx = tx + 4;
    float c = ss[cy][cx];
    float mx = -INFINITY;
#pragma unroll
    for (int dy = -2; dy <= 2; ++dy)
#pragma unroll
        for (int dx = -2; dx <= 2; ++dx) mx = fmaxf(mx, ss[cy + dy][cx + dx]);
    unsigned char nm = (c == mx && !supp[cy][cx]) ? 1 : 0;
    unsigned char fin = (unsigned char)(m[cy][cx] | nm);
    float v = s[cy][cx];
    int gy = by + ty, gx = bx + tx;
    bool keep = fin && (v > 0.0f) && gy >= 2 && gy < H - 2 && gx >= 2 && gx < W - 2;
    if (keep) {
        unsigned int p = (unsigned int)(gy * W + gx);
        unsigned long long key =
            ((unsigned long long)__float_as_uint(v) << 32) | (unsigned long long)(~p);
        unsigned int pos = atomicAdd(&lcnt, 1u);
        lkeys[pos] = key;
    }
    __syncthreads();
    if (tid == 0) lbase = lcnt ? atomicAdd(&cnt[b], lcnt) : 0u;
    __syncthreads();
    if (tid < (int)lcnt) {
        unsigned int slot = lbase + tid;
        if (slot < CAP) surv[(size_t)b * CAP + slot] = lkeys[tid];
    }
}

// bin index: monotone in key for float >= 2^-7 (bits[63:58]==0x0F); underflow -> bin 0
__device__ __forceinline__ int binOf(unsigned long long key) {
    return ((key >> 58) == 0x0Full) ? (int)((key >> 44) & (NB - 1)) : 0;
}

// ---- Fused exact top-4096: fine hist + scan -> kstar -> gather -> bitonic sort ----
__global__ __launch_bounds__(1024) void k_topk(const unsigned long long* __restrict__ surv,
                                               const unsigned int* __restrict__ cnt,
                                               unsigned long long* __restrict__ sorted) {
    __shared__ union {
        unsigned int hist[NB];            // 64 KB
        unsigned long long keys[TOPK];    // 32 KB
    } u;
    __shared__ unsigned long long cand[4096];  // 32 KB
    __shared__ unsigned int psum[1024];        // 4 KB
    __shared__ int sh_T;
    __shared__ unsigned int sh_r, sh_m, sh_pos;
    __shared__ unsigned long long sh_kstar;
    int b = blockIdx.x;
    int tid = (int)threadIdx.x;
    unsigned int n = cnt[b];
    if (n > CAP) n = CAP;
    const unsigned long long* sv = surv + (size_t)b * CAP;

    for (int i = tid; i < NB; i += 1024) u.hist[i] = 0;
    if (tid == 0) { sh_m = 0; sh_pos = 0; }
    __syncthreads();
    // pass 1: histogram
    for (unsigned int i = tid; i < n; i += 1024) atomicAdd(&u.hist[binOf(sv[i])], 1u);
    __syncthreads();
    // descending scan over bins (thread t owns 16 bins from the top)
    const int CH = NB / 1024;
    int hi = NB - 1 - tid * CH;
    unsigned int local = 0;
    for (int j = 0; j < CH; ++j) local += u.hist[hi - j];
    psum[tid] = local;
    __syncthreads();
    for (int off = 1; off < 1024; off <<= 1) {
        unsigned int v = (tid >= off) ? psum[tid - off] : 0u;
        __syncthreads();
        psum[tid] += v;
        __syncthreads();
    }
    unsigned int incl = psum[tid], excl = incl - local;
    unsigned int ntot = psum[1023];
    if (ntot > TOPK) {
        if (excl < TOPK && TOPK <= incl) {
            unsigned int cum = excl;
            for (int j = 0; j < CH; ++j) {
                unsigned int c = u.hist[hi - j];
                if (cum + c >= TOPK) {
                    sh_T = hi - j;
                    sh_r = TOPK - cum;
                    break;
                }
                cum += c;
            }
        }
    } else if (tid == 0) {
        sh_T = -1;
        sh_kstar = 0ull;
    }
    __syncthreads();
    int T = sh_T;  // block-uniform
    if (T >= 0) {
        // pass 2: collect threshold-bin candidates, exact rank-count for kstar
        for (unsigned int i = tid; i < n; i += 1024) {
            unsigned long long kk = sv[i];
            if (binOf(kk) == T) {
                unsigned int p = atomicAdd(&sh_m, 1u);
                if (p < 4096u) cand[p] = kk;
            }
        }
        __syncthreads();
        unsigned int m = sh_m;
        if (m > 4096u) m = 4096u;
        unsigned int r = sh_r;
        for (unsigned int i = tid; i < m; i += 1024) {
            unsigned long long ki = cand[i];
            unsigned int g = 0;
            for (unsigned int j = 0; j < m; ++j) g += (cand[j] > ki) ? 1u : 0u;
            if (g == r - 1) sh_kstar = ki;
        }
        __syncthreads();
    }
    unsigned long long kstar = sh_kstar;
    __syncthreads();  // done with u.hist; reuse as keys
    for (int i = tid; i < TOPK; i += 1024) u.keys[i] = 0ull;
    __syncthreads();
    // pass 3: gather keys >= kstar with wave-aggregated compaction
    int lane = tid & 63;
    for (unsigned int base = 0; base < n; base += 1024) {
        unsigned int i = base + (unsigned int)tid;
        unsigned long long kk = 0;
        bool keep = false;
        if (i < n) {
            kk = sv[i];
            keep = (kk >= kstar);
        }
        unsigned long long ball = __ballot(keep);
        unsigned int wcnt = (unsigned int)__popcll(ball);
        if (wcnt) {
            unsigned int wbase = 0;
            if (lane == 0) wbase = atomicAdd(&sh_pos, wcnt);
            wbase = (unsigned int)__shfl((int)wbase, 0);
            if (keep) {
                unsigned int off = (unsigned int)__popcll(ball & ((1ull << lane) - 1ull));
                unsigned int slot = wbase + off;
                if (slot < TOPK) u.keys[slot] = kk;
            }
        }
    }
    __syncthreads();
    // bitonic sort 4096 desc
    for (int k = 2; k <= TOPK; k <<= 1) {
        for (int j = k >> 1; j > 0; j >>= 1) {
            for (int p = tid; p < TOPK / 2; p += 1024) {
                int i = ((p & ~(j - 1)) << 1) | (p & (j - 1));
                int l = i | j;
                bool desc = ((i & k) == 0);
                unsigned long long a = u.keys[i], bb = u.keys[l];
                if ((a < bb) == desc) {
                    u.keys[i] = bb;
                    u.keys[l] = a;
                }
            }
            __syncthreads();
        }
    }
    for (int i = tid; i < TOPK; i += 1024) sorted[(size_t)b * TOPK + i] = u.keys[i];
}

// -------- Per-keypoint soft-argmax / dispersity / bilinear sample --------
__global__ __launch_bounds__(256) void k_out(const float* __restrict__ scores,
                                             const unsigned long long* __restrict__ sorted,
                                             float* __restrict__ out) {
    int gid = blockIdx.x * 256 + threadIdx.x;
    int b = gid / TOPK;
    int kp = gid & (TOPK - 1);
    const float* img = scores + (size_t)b * H * W;
    unsigned long long key = sorted[(size_t)b * TOPK + kp];
    unsigned int idx = ~(unsigned int)(key & 0xFFFFFFFFull);
    int ky = (int)(idx >> 10), kx = (int)(idx & 1023);
    ky = min(max(ky, 2), H - 3);
    kx = min(max(kx, 2), W - 3);
    float patch[25];
    float mx = -INFINITY;
#pragma unroll
    for (int dy = 0; dy < 5; ++dy)
#pragma unroll
        for (int dx = 0; dx < 5; ++dx) {
            float v = img[(ky + dy - 2) * W + (kx + dx - 2)];
            patch[dy * 5 + dx] = v;
            mx = fmaxf(mx, v);
        }
    float e[25];
    float ssum = 0.f, ex = 0.f, ey = 0.f;
#pragma unroll
    for (int p = 0; p < 25; ++p) {
        float t = expf((patch[p] - mx) / 0.1f);
        e[p] = t;
        ssum += t;
        ex += t * (float)((p % 5) - 2);
        ey += t * (float)((p / 5) - 2);
    }
    float xr = ex / ssum, yr = ey / ssum;
    float disp = 0.f;
#pragma unroll
    for (int p = 0; p < 25; ++p) {
        float ddx = ((float)((p % 5) - 2) - xr) * 0.5f;
        float ddy = ((float)((p / 5) - 2) - yr) * 0.5f;
        disp += e[p] * (ddx * ddx + ddy * ddy);
    }
    disp /= ssum;
    float kpx = ((float)kx + xr) / 1023.0f * 2.0f - 1.0f;
    float kpy = ((float)ky + yr) / 1023.0f * 2.0f - 1.0f;
    float px = (kpx + 1.0f) * 0.5f * 1023.0f;
    float py = (kpy + 1.0f) * 0.5f * 1023.0f;
    float fx = floorf(px), fy = floorf(py);
    float wx = px - fx, wy = py - fy;
    int x0 = (int)fminf(fmaxf(fx, 0.f), 1023.f);
    int x1 = (int)fminf(fmaxf(fx + 1.f, 0.f), 1023.f);
    int y0 = (int)fminf(fmaxf(fy, 0.f), 1023.f);
    int y1 = (int)fminf(fmaxf(fy + 1.f, 0.f), 1023.f);
    float v00 = img[y0 * W + x0], v01 = img[y0 * W + x1];
    float v10 = img[y1 * W + x0], v11 = img[y1 * W + x1];
    float sc = v00 * (1.f - wx) * (1.f - wy) + v01 * wx * (1.f - wy) +
               v10 * (1.f - wx) * wy + v11 * wx * wy;
    size_t kb = (size_t)b * TOPK + kp;
    out[kb * 2 + 0] = kpx;
    out[kb * 2 + 1] = kpy;
    out[(size_t)B * TOPK * 2 + kb] = disp;
    out[(size_t)B * TOPK * 3 + kb] = sc;
}

extern "C" void kernel_launch(void* const* d_in, const int* in_sizes, int n_in,
                              void* d_out, int out_size, void* d_ws, size_t ws_size,
                              hipStream_t stream) {
    const float* scores = (const float*)d_in[0];
    float* out = (float*)d_out;
    char* ws = (char*)d_ws;
    unsigned char* mask0 = (unsigned char*)(ws);
    unsigned char* mask1 = (unsigned char*)(ws + (size_t)(8u << 20));
    unsigned long long* surv = (unsigned long long*)(ws + (size_t)(16u << 20));
    unsigned int* cnt = (unsigned int*)(ws + (size_t)(24u << 20));
    unsigned long long* sorted = (unsigned long long*)(ws + (size_t)(24u << 20) + 4096);

    hipMemsetAsync(cnt, 0, B * sizeof(unsigned int), stream);

    dim3 blk(TS, TS);
    dim3 grd(W / TS, H / TS, B);
    k_init<<<grd, blk, 0, stream>>>(scores, mask0);
    k_iter<<<grd, blk, 0, stream>>>(scores, mask0, mask1);
    k_iter2<<<grd, blk, 0, stream>>>(scores, mask1, surv, cnt);
    k_topk<<<B, 1024, 0, stream>>>(surv, cnt, sorted);
    k_out<<<(B * TOPK) / 256, 256, 0, stream>>>(scores, sorted, out);
}

// Round 4
// 222.039 us; speedup vs baseline: 35.3011x; 2.1140x over previous
//
#include <hip/hip_runtime.h>
#include <math.h>

#define H 1024
#define W 1024
#define B 8
#define TOPK 4096
#define CAP 131072
#define NB 16384
#define TILE 44
#define REG 64
#define GD 24  // ceil(1024/44)

__device__ __forceinline__ float hmax5(float v) {
    float a = __shfl_up(v, 1);
    float b = __shfl_up(v, 2);
    float c = __shfl_down(v, 1);
    float d = __shfl_down(v, 2);
    return fmaxf(fmaxf(fmaxf(a, b), fmaxf(c, d)), v);
}

// ---- Fused 3-round NMS + survivor compaction ----
// Region 64x64 per block (tile 44x44 + halo 10). 4 waves x 16 rows, lane = column.
__global__ __launch_bounds__(256) void k_nms(const float* __restrict__ scores,
                                             unsigned long long* __restrict__ surv,
                                             unsigned int* __restrict__ cnt) {
    __shared__ float h[REG][REG];              // horizontal-max scratch (per round)
    __shared__ unsigned long long ma[REG];     // round0 mask / final mask
    __shared__ unsigned long long mb[REG];     // round1 mask
    __shared__ unsigned long long sup[REG];    // dilated (suppression) mask
    __shared__ unsigned long long skeys[384];
    __shared__ unsigned int lcnt, gbase;
    const int b = blockIdx.z;
    const int gx0 = blockIdx.x * TILE - 10;
    const int gy0 = blockIdx.y * TILE - 10;
    const float* img = scores + (size_t)b * H * W;
    const int tid = (int)threadIdx.x;
    const int lane = tid & 63;
    const int rbase = (tid >> 6) * 16;
    if (tid == 0) lcnt = 0;

    const int gx = gx0 + lane;
    const bool cin = (gx >= 0 && gx < W);
    float sv[16], hreg[16], ssv[16];
    for (int i = 0; i < 16; ++i) {
        int gy = gy0 + rbase + i;
        sv[i] = (cin && gy >= 0 && gy < H) ? img[(size_t)gy * W + gx] : -INFINITY;
    }

    // ---------- round 0: m0 = (s == maxpool5(s)), valid rows/cols [2,61] ----------
    for (int i = 0; i < 16; ++i) {
        hreg[i] = hmax5(sv[i]);
        h[rbase + i][lane] = hreg[i];
    }
    __syncthreads();
    for (int i = 0; i < 16; ++i) {
        int r = rbase + i;
        if (r < 2 || r > 61) continue;
        float v0 = (i >= 2) ? hreg[i - 2] : h[r - 2][lane];
        float v1 = (i >= 1) ? hreg[i - 1] : h[r - 1][lane];
        float v3 = (i <= 14) ? hreg[i + 1] : h[r + 1][lane];
        float v4 = (i <= 13) ? hreg[i + 2] : h[r + 2][lane];
        float vm = fmaxf(fmaxf(fmaxf(v0, v1), fmaxf(v3, v4)), hreg[i]);
        bool bit = (sv[i] == vm) && (sv[i] != -INFINITY) && lane >= 2 && lane <= 61;
        unsigned long long ball = __ballot(bit);
        if (lane == 0) ma[r] = ball;
    }
    __syncthreads();

    // ---------- round 1: supp [4,59]; mask1 = m0 | new_max, valid [6,57] ----------
    if (tid >= 4 && tid <= 59) {
        unsigned long long o = ma[tid - 2] | ma[tid - 1] | ma[tid] | ma[tid + 1] | ma[tid + 2];
        sup[tid] = o | (o << 1) | (o >> 1) | (o << 2) | (o >> 2);
    }
    __syncthreads();
    for (int i = 0; i < 16; ++i) {
        int r = rbase + i;
        if (r < 4 || r > 59) continue;
        bool sb = (sup[r] >> lane) & 1ull;
        ssv[i] = (sv[i] == -INFINITY) ? -INFINITY : (sb ? 0.0f : sv[i]);
        hreg[i] = hmax5(ssv[i]);
        h[r][lane] = hreg[i];
    }
    __syncthreads();
    for (int i = 0; i < 16; ++i) {
        int r = rbase + i;
        if (r < 6 || r > 57) continue;
        float v0 = (i >= 2) ? hreg[i - 2] : h[r - 2][lane];
        float v1 = (i >= 1) ? hreg[i - 1] : h[r - 1][lane];
        float v3 = (i <= 14) ? hreg[i + 1] : h[r + 1][lane];
        float v4 = (i <= 13) ? hreg[i + 2] : h[r + 2][lane];
        float vm = fmaxf(fmaxf(fmaxf(v0, v1), fmaxf(v3, v4)), hreg[i]);
        bool sb = (sup[r] >> lane) & 1ull;
        bool nm = (ssv[i] == vm) && !sb && (sv[i] != -INFINITY) && lane >= 6 && lane <= 57;
        unsigned long long ball = __ballot(nm);
        if (lane == 0) mb[r] = ma[r] | ball;
    }
    __syncthreads();

    // ---------- round 2: supp [8,55]; final mask = mask1 | new_max, valid [10,53] ----------
    if (tid >= 8 && tid <= 55) {
        unsigned long long o = mb[tid - 2] | mb[tid - 1] | mb[tid] | mb[tid + 1] | mb[tid + 2];
        sup[tid] = o | (o << 1) | (o >> 1) | (o << 2) | (o >> 2);
    }
    __syncthreads();
    for (int i = 0; i < 16; ++i) {
        int r = rbase + i;
        if (r < 8 || r > 55) continue;
        bool sb = (sup[r] >> lane) & 1ull;
        ssv[i] = (sv[i] == -INFINITY) ? -INFINITY : (sb ? 0.0f : sv[i]);
        hreg[i] = hmax5(ssv[i]);
        h[r][lane] = hreg[i];
    }
    __syncthreads();
    for (int i = 0; i < 16; ++i) {
        int r = rbase + i;
        if (r < 10 || r > 53) continue;
        float v0 = (i >= 2) ? hreg[i - 2] : h[r - 2][lane];
        float v1 = (i >= 1) ? hreg[i - 1] : h[r - 1][lane];
        float v3 = (i <= 14) ? hreg[i + 1] : h[r + 1][lane];
        float v4 = (i <= 13) ? hreg[i + 2] : h[r + 2][lane];
        float vm = fmaxf(fmaxf(fmaxf(v0, v1), fmaxf(v3, v4)), hreg[i]);
        bool sb = (sup[r] >> lane) & 1ull;
        bool nm = (ssv[i] == vm) && !sb && (sv[i] != -INFINITY) && lane >= 10 && lane <= 53;
        unsigned long long ball = __ballot(nm);
        if (lane == 0) ma[r] = mb[r] | ball;
    }
    __syncthreads();

    // ---------- survivor compaction (tile = rows/cols [10,53]) ----------
    for (int i = 0; i < 16; ++i) {
        int r = rbase + i;
        if (r < 10 || r > 53) continue;
        int gy = gy0 + r;
        bool keep = false;
        unsigned long long key = 0ull;
        if (lane >= 10 && lane <= 53) {
            bool bit = (ma[r] >> lane) & 1ull;
            float v = sv[i];
            if (bit && v > 0.0f && gx >= 2 && gx < W - 2 && gy >= 2 && gy < H - 2) {
                keep = true;
                unsigned int p = (unsigned int)(gy * W + gx);
                key = ((unsigned long long)__float_as_uint(v) << 32) |
                      (unsigned long long)(~p);
            }
        }
        unsigned long long ball = __ballot(keep);
        unsigned int wcnt = (unsigned int)__popcll(ball);
        if (wcnt) {
            unsigned int wb = 0;
            if (lane == 0) wb = atomicAdd(&lcnt, wcnt);
            wb = (unsigned int)__shfl((int)wb, 0);
            if (keep) {
                unsigned int off = (unsigned int)__popcll(ball & ((1ull << lane) - 1ull));
                skeys[wb + off] = key;
            }
        }
    }
    __syncthreads();
    if (tid == 0) gbase = lcnt ? atomicAdd(&cnt[b], lcnt) : 0u;
    __syncthreads();
    unsigned int nk = lcnt;
    for (unsigned int i = tid; i < nk; i += 256)
        surv[(size_t)b * CAP + gbase + i] = skeys[i];
}

// bin index: monotone in key for float >= 2^-7 (bits[63:58]==0x0F); underflow -> bin 0
__device__ __forceinline__ int binOf(unsigned long long key) {
    return ((key >> 58) == 0x0Full) ? (int)((key >> 44) & (NB - 1)) : 0;
}

// ---- Fused exact top-4096: fine hist + scan -> kstar -> gather -> bitonic sort ----
__global__ __launch_bounds__(1024) void k_topk(const unsigned long long* __restrict__ surv,
                                               const unsigned int* __restrict__ cnt,
                                               unsigned long long* __restrict__ sorted) {
    __shared__ union {
        unsigned int hist[NB];
        unsigned long long keys[TOPK];
    } u;
    __shared__ unsigned long long cand[4096];
    __shared__ unsigned int psum[1024];
    __shared__ int sh_T;
    __shared__ unsigned int sh_r, sh_m, sh_pos;
    __shared__ unsigned long long sh_kstar;
    int b = blockIdx.x;
    int tid = (int)threadIdx.x;
    unsigned int n = cnt[b];
    if (n > CAP) n = CAP;
    const unsigned long long* sv = surv + (size_t)b * CAP;

    for (int i = tid; i < NB; i += 1024) u.hist[i] = 0;
    if (tid == 0) { sh_m = 0; sh_pos = 0; }
    __syncthreads();
    for (unsigned int i = tid; i < n; i += 1024) atomicAdd(&u.hist[binOf(sv[i])], 1u);
    __syncthreads();
    const int CH = NB / 1024;
    int hi = NB - 1 - tid * CH;
    unsigned int local = 0;
    for (int j = 0; j < CH; ++j) local += u.hist[hi - j];
    psum[tid] = local;
    __syncthreads();
    for (int off = 1; off < 1024; off <<= 1) {
        unsigned int v = (tid >= off) ? psum[tid - off] : 0u;
        __syncthreads();
        psum[tid] += v;
        __syncthreads();
    }
    unsigned int incl = psum[tid], excl = incl - local;
    unsigned int ntot = psum[1023];
    if (ntot > TOPK) {
        if (excl < TOPK && TOPK <= incl) {
            unsigned int cum = excl;
            for (int j = 0; j < CH; ++j) {
                unsigned int c = u.hist[hi - j];
                if (cum + c >= TOPK) {
                    sh_T = hi - j;
                    sh_r = TOPK - cum;
                    break;
                }
                cum += c;
            }
        }
    } else if (tid == 0) {
        sh_T = -1;
        sh_kstar = 0ull;
    }
    __syncthreads();
    int T = sh_T;
    if (T >= 0) {
        for (unsigned int i = tid; i < n; i += 1024) {
            unsigned long long kk = sv[i];
            if (binOf(kk) == T) {
                unsigned int p = atomicAdd(&sh_m, 1u);
                if (p < 4096u) cand[p] = kk;
            }
        }
        __syncthreads();
        unsigned int m = sh_m;
        if (m > 4096u) m = 4096u;
        unsigned int r = sh_r;
        for (unsigned int i = tid; i < m; i += 1024) {
            unsigned long long ki = cand[i];
            unsigned int g = 0;
            for (unsigned int j = 0; j < m; ++j) g += (cand[j] > ki) ? 1u : 0u;
            if (g == r - 1) sh_kstar = ki;
        }
        __syncthreads();
    }
    unsigned long long kstar = sh_kstar;
    __syncthreads();
    for (int i = tid; i < TOPK; i += 1024) u.keys[i] = 0ull;
    __syncthreads();
    int lane = tid & 63;
    for (unsigned int base = 0; base < n; base += 1024) {
        unsigned int i = base + (unsigned int)tid;
        unsigned long long kk = 0;
        bool keep = false;
        if (i < n) {
            kk = sv[i];
            keep = (kk >= kstar);
        }
        unsigned long long ball = __ballot(keep);
        unsigned int wcnt = (unsigned int)__popcll(ball);
        if (wcnt) {
            unsigned int wbase = 0;
            if (lane == 0) wbase = atomicAdd(&sh_pos, wcnt);
            wbase = (unsigned int)__shfl((int)wbase, 0);
            if (keep) {
                unsigned int off = (unsigned int)__popcll(ball & ((1ull << lane) - 1ull));
                unsigned int slot = wbase + off;
                if (slot < TOPK) u.keys[slot] = kk;
            }
        }
    }
    __syncthreads();
    for (int k = 2; k <= TOPK; k <<= 1) {
        for (int j = k >> 1; j > 0; j >>= 1) {
            for (int p = tid; p < TOPK / 2; p += 1024) {
                int i = ((p & ~(j - 1)) << 1) | (p & (j - 1));
                int l = i | j;
                bool desc = ((i & k) == 0);
                unsigned long long a = u.keys[i], bb = u.keys[l];
                if ((a < bb) == desc) {
                    u.keys[i] = bb;
                    u.keys[l] = a;
                }
            }
            __syncthreads();
        }
    }
    for (int i = tid; i < TOPK; i += 1024) sorted[(size_t)b * TOPK + i] = u.keys[i];
}

// -------- Per-keypoint soft-argmax / dispersity / bilinear sample --------
__global__ __launch_bounds__(256) void k_out(const float* __restrict__ scores,
                                             const unsigned long long* __restrict__ sorted,
                                             float* __restrict__ out) {
    int gid = blockIdx.x * 256 + threadIdx.x;
    int b = gid / TOPK;
    int kp = gid & (TOPK - 1);
    const float* img = scores + (size_t)b * H * W;
    unsigned long long key = sorted[(size_t)b * TOPK + kp];
    unsigned int idx = ~(unsigned int)(key & 0xFFFFFFFFull);
    int ky = (int)(idx >> 10), kx = (int)(idx & 1023);
    ky = min(max(ky, 2), H - 3);
    kx = min(max(kx, 2), W - 3);
    float patch[25];
    float mx = -INFINITY;
#pragma unroll
    for (int dy = 0; dy < 5; ++dy)
#pragma unroll
        for (int dx = 0; dx < 5; ++dx) {
            float v = img[(ky + dy - 2) * W + (kx + dx - 2)];
            patch[dy * 5 + dx] = v;
            mx = fmaxf(mx, v);
        }
    float e[25];
    float ssum = 0.f, ex = 0.f, ey = 0.f;
#pragma unroll
    for (int p = 0; p < 25; ++p) {
        float t = expf((patch[p] - mx) / 0.1f);
        e[p] = t;
        ssum += t;
        ex += t * (float)((p % 5) - 2);
        ey += t * (float)((p / 5) - 2);
    }
    float xr = ex / ssum, yr = ey / ssum;
    float disp = 0.f;
#pragma unroll
    for (int p = 0; p < 25; ++p) {
        float ddx = ((float)((p % 5) - 2) - xr) * 0.5f;
        float ddy = ((float)((p / 5) - 2) - yr) * 0.5f;
        disp += e[p] * (ddx * ddx + ddy * ddy);
    }
    disp /= ssum;
    float kpx = ((float)kx + xr) / 1023.0f * 2.0f - 1.0f;
    float kpy = ((float)ky + yr) / 1023.0f * 2.0f - 1.0f;
    float px = (kpx + 1.0f) * 0.5f * 1023.0f;
    float py = (kpy + 1.0f) * 0.5f * 1023.0f;
    float fx = floorf(px), fy = floorf(py);
    float wx = px - fx, wy = py - fy;
    int x0 = (int)fminf(fmaxf(fx, 0.f), 1023.f);
    int x1 = (int)fminf(fmaxf(fx + 1.f, 0.f), 1023.f);
    int y0 = (int)fminf(fmaxf(fy, 0.f), 1023.f);
    int y1 = (int)fminf(fmaxf(fy + 1.f, 0.f), 1023.f);
    float v00 = img[y0 * W + x0], v01 = img[y0 * W + x1];
    float v10 = img[y1 * W + x0], v11 = img[y1 * W + x1];
    float sc = v00 * (1.f - wx) * (1.f - wy) + v01 * wx * (1.f - wy) +
               v10 * (1.f - wx) * wy + v11 * wx * wy;
    size_t kb = (size_t)b * TOPK + kp;
    out[kb * 2 + 0] = kpx;
    out[kb * 2 + 1] = kpy;
    out[(size_t)B * TOPK * 2 + kb] = disp;
    out[(size_t)B * TOPK * 3 + kb] = sc;
}

extern "C" void kernel_launch(void* const* d_in, const int* in_sizes, int n_in,
                              void* d_out, int out_size, void* d_ws, size_t ws_size,
                              hipStream_t stream) {
    const float* scores = (const float*)d_in[0];
    float* out = (float*)d_out;
    char* ws = (char*)d_ws;
    unsigned long long* surv = (unsigned long long*)ws;                       // 8 MB
    unsigned int* cnt = (unsigned int*)(ws + (size_t)B * CAP * 8);            // 32 B
    unsigned long long* sorted = (unsigned long long*)(ws + (size_t)B * CAP * 8 + 4096);

    hipMemsetAsync(cnt, 0, B * sizeof(unsigned int), stream);

    dim3 blk(256);
    dim3 grd(GD, GD, B);
    k_nms<<<grd, blk, 0, stream>>>(scores, surv, cnt);
    k_topk<<<B, 1024, 0, stream>>>(surv, cnt, sorted);
    k_out<<<(B * TOPK) / 256, 256, 0, stream>>>(scores, sorted, out);
}

// Round 5
// 167.210 us; speedup vs baseline: 46.8764x; 1.3279x over previous
//
#include <hip/hip_runtime.h>
#include <math.h>

#define H 1024
#define W 1024
#define B 8
#define TOPK 4096
#define CAP 131072
#define NB 16384
#define TILE_X 108
#define TILE_Y 44
#define GDX 10
#define GDY 24

typedef unsigned long long u64;
typedef unsigned int u32;

// ================= Fused 3-round NMS + survivor compaction =================
// Region 128 wide x 64 tall per block; lane owns 2 adjacent columns (float2).
// 256 threads = 4 waves x 16 rows. Tile = [10,117]x[10,53] (108x44).
// Masks: split bitboards per row: E bit j = col 2j, O bit j = col 2j+1.

#define ROUND_A(VR0, VR1, USE_SUPP)                                               \
    _Pragma("unroll") for (int i = 0; i < 16; ++i) {                              \
        int r = rbase + i;                                                        \
        if (r < (VR0) || r > (VR1)) continue;                                     \
        float x = svx[i], y = svy[i];                                             \
        if (USE_SUPP) {                                                           \
            if ((spE[r] >> lane) & 1ull) x = (x == -INFINITY) ? x : 0.0f;         \
            if ((spO[r] >> lane) & 1ull) y = (y == -INFINITY) ? y : 0.0f;         \
        }                                                                         \
        float ux = __shfl_up(x, 1), uy = __shfl_up(y, 1);                         \
        float dxx = __shfl_down(x, 1), dyy = __shfl_down(y, 1);                   \
        float m01 = fmaxf(x, y);                                                  \
        float h0 = fmaxf(fmaxf(ux, uy), fmaxf(m01, dxx));                         \
        float h1 = fmaxf(fmaxf(uy, m01), fmaxf(dxx, dyy));                        \
        h0r[i] = h0;                                                              \
        h1r[i] = h1;                                                              \
        if (i == 0 || i == 1 || i == 14 || i == 15) {                             \
            int k = (i < 2) ? i : i - 12;                                         \
            *(float2*)&hb[w * 4 + k][2 * lane] = make_float2(h0, h1);             \
        }                                                                         \
    }

#define ROUND_B(VV0, VV1, CMIN, CMAX, USE_SUPP, OUTE, OUTO, INE, INO, FIRST)      \
    _Pragma("unroll") for (int i = 0; i < 16; ++i) {                              \
        int r = rbase + i;                                                        \
        if (r < (VV0) || r > (VV1)) continue;                                     \
        float v0x, v0y, v1x, v1y, v3x, v3y, v4x, v4y;                             \
        if (i >= 2) { v0x = h0r[i - 2]; v0y = h1r[i - 2]; }                       \
        else { int k = (i == 0) ? 2 : 3;                                          \
               float2 t = *(const float2*)&hb[(w - 1) * 4 + k][2 * lane];         \
               v0x = t.x; v0y = t.y; }                                            \
        if (i >= 1) { v1x = h0r[i - 1]; v1y = h1r[i - 1]; }                       \
        else { float2 t = *(const float2*)&hb[(w - 1) * 4 + 3][2 * lane];         \
               v1x = t.x; v1y = t.y; }                                            \
        if (i <= 14) { v3x = h0r[i + 1]; v3y = h1r[i + 1]; }                      \
        else { float2 t = *(const float2*)&hb[(w + 1) * 4 + 0][2 * lane];         \
               v3x = t.x; v3y = t.y; }                                            \
        if (i <= 13) { v4x = h0r[i + 2]; v4y = h1r[i + 2]; }                      \
        else { int k = (i == 14) ? 0 : 1;                                         \
               float2 t = *(const float2*)&hb[(w + 1) * 4 + k][2 * lane];         \
               v4x = t.x; v4y = t.y; }                                            \
        float vm0 = fmaxf(fmaxf(fmaxf(v0x, v1x), fmaxf(v3x, v4x)), h0r[i]);       \
        float vm1 = fmaxf(fmaxf(fmaxf(v0y, v1y), fmaxf(v3y, v4y)), h1r[i]);       \
        float x = svx[i], y = svy[i];                                             \
        bool sb0 = false, sb1 = false;                                            \
        if (USE_SUPP) {                                                           \
            sb0 = (spE[r] >> lane) & 1ull;                                        \
            sb1 = (spO[r] >> lane) & 1ull;                                        \
            if (sb0) x = (x == -INFINITY) ? x : 0.0f;                             \
            if (sb1) y = (y == -INFINITY) ? y : 0.0f;                             \
        }                                                                         \
        int c0 = 2 * lane;                                                        \
        bool bit0 = (x == vm0) && !sb0 && (svx[i] != -INFINITY) &&                \
                    c0 >= (CMIN) && c0 <= (CMAX);                                 \
        bool bit1 = (y == vm1) && !sb1 && (svy[i] != -INFINITY) &&                \
                    (c0 + 1) >= (CMIN) && (c0 + 1) <= (CMAX);                     \
        u64 bE = __ballot(bit0), bO = __ballot(bit1);                             \
        if (lane == 0) {                                                          \
            OUTE[r] = ((FIRST) ? 0ull : INE[r]) | bE;                             \
            OUTO[r] = ((FIRST) ? 0ull : INO[r]) | bO;                             \
        }                                                                         \
    }

#define DILATE(R0, R1, INE, INO)                                                  \
    if (tid >= (R0) && tid <= (R1)) {                                             \
        int rr = tid;                                                             \
        u64 e = INE[rr - 2] | INE[rr - 1] | INE[rr] | INE[rr + 1] | INE[rr + 2];  \
        u64 o = INO[rr - 2] | INO[rr - 1] | INO[rr] | INO[rr + 1] | INO[rr + 2];  \
        spE[rr] = e | (e << 1) | (e >> 1) | o | (o << 1);                         \
        spO[rr] = o | (o << 1) | (o >> 1) | e | (e >> 1);                         \
    }

__global__ __launch_bounds__(256) void k_nms(const float* __restrict__ scores,
                                             u64* __restrict__ surv,
                                             u32* __restrict__ cnt) {
    __shared__ float hb[16][128];
    __shared__ u64 maE[64], maO[64], mbE[64], mbO[64], spE[64], spO[64];
    __shared__ u64 skeys[640];
    __shared__ u32 lcnt, gbase;
    const int b = blockIdx.z;
    const int gx0 = blockIdx.x * TILE_X - 10;
    const int gy0 = blockIdx.y * TILE_Y - 10;
    const float* img = scores + (size_t)b * H * W;
    const int tid = (int)threadIdx.x, lane = tid & 63, w = tid >> 6, rbase = w * 16;
    const int gx = gx0 + 2 * lane;
    if (tid == 0) lcnt = 0;

    float svx[16], svy[16], h0r[16], h1r[16];
#pragma unroll
    for (int i = 0; i < 16; ++i) {
        int gy = gy0 + rbase + i;
        float x = -INFINITY, y = -INFINITY;
        if (gy >= 0 && gy < H) {
            const float* row = img + (size_t)gy * W;
            if (gx >= 0 && gx + 1 < W) {
                float2 t = *(const float2*)(row + gx);
                x = t.x; y = t.y;
            } else if (gx >= 0 && gx < W) {
                x = row[gx];
            }
        }
        svx[i] = x; svy[i] = y;
    }

    // round 0: mask0, rows [2,61] cols [2,125]
    ROUND_A(0, 63, false)
    __syncthreads();
    ROUND_B(2, 61, 2, 125, false, maE, maO, maE, maO, 1)
    __syncthreads();
    // round 1: supp rows [4,59]; mask1 rows [6,57] cols [6,121]
    DILATE(4, 59, maE, maO)
    __syncthreads();
    ROUND_A(4, 59, true)
    __syncthreads();
    ROUND_B(6, 57, 6, 121, true, mbE, mbO, maE, maO, 0)
    __syncthreads();
    // round 2: supp rows [8,55]; final rows [10,53] cols [10,117]
    DILATE(8, 55, mbE, mbO)
    __syncthreads();
    ROUND_A(8, 55, true)
    __syncthreads();
    ROUND_B(10, 53, 10, 117, true, maE, maO, mbE, mbO, 0)
    __syncthreads();

    // survivor compaction
#pragma unroll
    for (int i = 0; i < 16; ++i) {
        int r = rbase + i;
        if (r < 10 || r > 53) continue;
        int gy = gy0 + r;
        u64 me = maE[r], mo = maO[r];
        int c0 = 2 * lane;
        if (c0 >= 10 && c0 <= 117 && ((me >> lane) & 1ull) && svx[i] > 0.0f &&
            gx >= 2 && gx < W - 2 && gy >= 2 && gy < H - 2) {
            u32 pos = atomicAdd(&lcnt, 1u);
            if (pos < 640u) {
                u32 p = (u32)(gy * W + gx);
                skeys[pos] = ((u64)__float_as_uint(svx[i]) << 32) | (u64)(~p);
            }
        }
        if (c0 + 1 >= 10 && c0 + 1 <= 117 && ((mo >> lane) & 1ull) && svy[i] > 0.0f &&
            gx + 1 >= 2 && gx + 1 < W - 2 && gy >= 2 && gy < H - 2) {
            u32 pos = atomicAdd(&lcnt, 1u);
            if (pos < 640u) {
                u32 p = (u32)(gy * W + gx + 1);
                skeys[pos] = ((u64)__float_as_uint(svy[i]) << 32) | (u64)(~p);
            }
        }
    }
    __syncthreads();
    u32 nk = lcnt < 640u ? lcnt : 640u;
    if (tid == 0) gbase = nk ? atomicAdd(&cnt[b], nk) : 0u;
    __syncthreads();
    for (u32 i = tid; i < nk; i += 256)
        surv[(size_t)b * CAP + gbase + i] = skeys[i];
}

// bin monotone in key for v in [2^-7, 2); underflow -> bin 0
__device__ __forceinline__ int binOf(u64 key) {
    return ((key >> 58) == 0x0Full) ? (int)((key >> 44) & (NB - 1)) : 0;
}

// ===== Exact sorted top-4096 via histogram slotting (no bitonic sort) =====
__global__ __launch_bounds__(1024) void k_topk(const u64* __restrict__ surv,
                                               const u32* __restrict__ cnt,
                                               u64* __restrict__ sorted) {
    __shared__ u32 hist[NB];   // counts, then (base_slot<<16)|placed
    __shared__ u64 keys[TOPK];
    __shared__ u64 cand[4096];
    __shared__ u32 psum[1024];
    __shared__ int sh_T;
    __shared__ u32 sh_r, sh_m;
    int b = blockIdx.x, tid = (int)threadIdx.x;
    u32 n = cnt[b];
    if (n > CAP) n = CAP;
    const u64* sv = surv + (size_t)b * CAP;
    for (int i = tid; i < NB; i += 1024) hist[i] = 0;
    for (int i = tid; i < TOPK; i += 1024) keys[i] = 0ull;
    if (tid == 0) { sh_m = 0; sh_T = 0; sh_r = 0; }
    __syncthreads();
    for (u32 i = tid; i < n; i += 1024) atomicAdd(&hist[binOf(sv[i])], 1u);
    __syncthreads();
    u32 cnts[16];
    int hi = NB - 1 - tid * 16;
    u32 local = 0;
#pragma unroll
    for (int j = 0; j < 16; ++j) { cnts[j] = hist[hi - j]; local += cnts[j]; }
    psum[tid] = local;
    __syncthreads();
    for (int off = 1; off < 1024; off <<= 1) {
        u32 v = (tid >= off) ? psum[tid - off] : 0u;
        __syncthreads();
        psum[tid] += v;
        __syncthreads();
    }
    u32 incl = psum[tid], excl = incl - local, ntot = psum[1023];
    if (ntot > TOPK) {
        if (excl < TOPK && TOPK <= incl) {
            u32 cum = excl;
#pragma unroll
            for (int j = 0; j < 16; ++j) {
                if (cum + cnts[j] >= TOPK) { sh_T = hi - j; sh_r = TOPK - cum; break; }
                cum += cnts[j];
            }
        }
    } else if (tid == 0) { sh_T = -1; sh_r = 0; }
    __syncthreads();
    int T = sh_T;
    u32 r = sh_r;
    {   // overwrite hist with per-bin base output slots
        u32 cum = excl;
#pragma unroll
        for (int j = 0; j < 16; ++j) { u32 c = cnts[j]; hist[hi - j] = cum << 16; cum += c; }
    }
    __syncthreads();
    // gather: bins > T -> contiguous segments in keys[]; bin T -> cand[]
    for (u32 i = tid; i < n; i += 1024) {
        u64 kk = sv[i];
        int bb = binOf(kk);
        if (bb > T) {
            u32 old = atomicAdd(&hist[bb], 1u);
            keys[(old >> 16) + (old & 0xFFFFu)] = kk;
        } else if (bb == T) {
            u32 p = atomicAdd(&sh_m, 1u);
            if (p < 4096u) cand[p] = kk;
        }
    }
    __syncthreads();
    // exact ranks within threshold bin -> final slots directly
    if (T >= 0) {
        u32 m = sh_m;
        if (m > 4096u) m = 4096u;
        u32 baseT = hist[T] >> 16;
        for (u32 i = tid; i < m; i += 1024) {
            u64 ki = cand[i];
            u32 g = 0;
            for (u32 j = 0; j < m; ++j) g += (cand[j] > ki) ? 1u : 0u;
            if (g < r) keys[baseT + g] = ki;
        }
    }
    __syncthreads();
    // within-segment ranking -> sorted global write
    u64* dst = sorted + (size_t)b * TOPK;
    for (int s = tid; s < TOPK; s += 1024) {
        u64 kk = keys[s];
        if (kk == 0ull) { dst[s] = 0ull; continue; }
        int bb = binOf(kk);
        if (bb == T) { dst[s] = kk; continue; }
        u32 h = hist[bb];
        u32 base = h >> 16, c = h & 0xFFFFu;
        u32 g = 0;
        for (u32 j = 0; j < c; ++j) g += (keys[base + j] > kk) ? 1u : 0u;
        dst[base + g] = kk;
    }
}

// -------- Per-keypoint soft-argmax / dispersity / bilinear sample --------
__global__ __launch_bounds__(64) void k_out(const float* __restrict__ scores,
                                            const u64* __restrict__ sorted,
                                            float* __restrict__ out) {
    int gid = blockIdx.x * 64 + threadIdx.x;
    int b = gid / TOPK;
    int kp = gid & (TOPK - 1);
    const float* img = scores + (size_t)b * H * W;
    u64 key = sorted[(size_t)b * TOPK + kp];
    u32 idx = ~(u32)(key & 0xFFFFFFFFull);
    int ky = (int)(idx >> 10), kx = (int)(idx & 1023);
    ky = min(max(ky, 2), H - 3);
    kx = min(max(kx, 2), W - 3);
    float patch[25];
    float mx = -INFINITY;
#pragma unroll
    for (int dy = 0; dy < 5; ++dy)
#pragma unroll
        for (int dx = 0; dx < 5; ++dx) {
            float v = img[(ky + dy - 2) * W + (kx + dx - 2)];
            patch[dy * 5 + dx] = v;
            mx = fmaxf(mx, v);
        }
    float e[25];
    float ssum = 0.f, ex = 0.f, ey = 0.f;
#pragma unroll
    for (int p = 0; p < 25; ++p) {
        float t = expf((patch[p] - mx) / 0.1f);
        e[p] = t;
        ssum += t;
        ex += t * (float)((p % 5) - 2);
        ey += t * (float)((p / 5) - 2);
    }
    float xr = ex / ssum, yr = ey / ssum;
    float disp = 0.f;
#pragma unroll
    for (int p = 0; p < 25; ++p) {
        float ddx = ((float)((p % 5) - 2) - xr) * 0.5f;
        float ddy = ((float)((p / 5) - 2) - yr) * 0.5f;
        disp += e[p] * (ddx * ddx + ddy * ddy);
    }
    disp /= ssum;
    float kpx = ((float)kx + xr) / 1023.0f * 2.0f - 1.0f;
    float kpy = ((float)ky + yr) / 1023.0f * 2.0f - 1.0f;
    float px = (kpx + 1.0f) * 0.5f * 1023.0f;
    float py = (kpy + 1.0f) * 0.5f * 1023.0f;
    float fx = floorf(px), fy = floorf(py);
    float wx = px - fx, wy = py - fy;
    int x0 = (int)fminf(fmaxf(fx, 0.f), 1023.f);
    int x1 = (int)fminf(fmaxf(fx + 1.f, 0.f), 1023.f);
    int y0 = (int)fminf(fmaxf(fy, 0.f), 1023.f);
    int y1 = (int)fminf(fmaxf(fy + 1.f, 0.f), 1023.f);
    float v00 = img[y0 * W + x0], v01 = img[y0 * W + x1];
    float v10 = img[y1 * W + x0], v11 = img[y1 * W + x1];
    float sc = v00 * (1.f - wx) * (1.f - wy) + v01 * wx * (1.f - wy) +
               v10 * (1.f - wx) * wy + v11 * wx * wy;
    size_t kb = (size_t)b * TOPK + kp;
    out[kb * 2 + 0] = kpx;
    out[kb * 2 + 1] = kpy;
    out[(size_t)B * TOPK * 2 + kb] = disp;
    out[(size_t)B * TOPK * 3 + kb] = sc;
}

extern "C" void kernel_launch(void* const* d_in, const int* in_sizes, int n_in,
                              void* d_out, int out_size, void* d_ws, size_t ws_size,
                              hipStream_t stream) {
    const float* scores = (const float*)d_in[0];
    float* out = (float*)d_out;
    char* ws = (char*)d_ws;
    u64* surv = (u64*)ws;                                    // 8 MB
    u32* cnt = (u32*)(ws + (size_t)B * CAP * 8);             // 32 B
    u64* sorted = (u64*)(ws + (size_t)B * CAP * 8 + 4096);   // 256 KB

    hipMemsetAsync(cnt, 0, B * sizeof(u32), stream);

    k_nms<<<dim3(GDX, GDY, B), 256, 0, stream>>>(scores, surv, cnt);
    k_topk<<<B, 1024, 0, stream>>>(surv, cnt, sorted);
    k_out<<<(B * TOPK) / 64, 64, 0, stream>>>(scores, sorted, out);
}